// Round 5
// baseline (484.944 us; speedup 1.0000x reference)
//
#include <hip/hip_runtime.h>
#include <math.h>

// GCN_homo: h = relu(D^-1/2 (A+I) D^-1/2 (x@Wg) + bg); MLP 16->16->32->1; sigmoid.
// N=100000, F=512, E=3200000. fp32; edge_index int32.
// R9 = R8 (verified 484.0us) with the scan kernel DELETED:
//  - each k_bscatter block redundantly computes the full column scan from bh
//    (800 KB, L2-resident, fully parallel; no spin/fence/flag) -> own row
//    prefix + bucket starts in LDS. Block 0 writes bstart[] for k_bcsr.
//  - k_xw unroll 4->8 (deeper load pipeline; xw runs at ~6 waves/CU).
// Pipeline: xw_bcount -> bscatter -> bcsr -> gather_mlp  (4 dispatches).

static constexpr int F = 512;
static constexpr int C = 16;
static constexpr int BSH = 7;       // 128 nodes per bucket
static constexpr int BSZ = 128;
static constexpr int NBMAX = 1024;  // max buckets (n <= 131072)
static constexpr int EPB = 16384;   // edges per partition block

// K1 fused: blocks [0,gb) -> xw rows; blocks [gb,gb+geb) -> bucket histograms.
__global__ __launch_bounds__(256) void k_xw_bcount(const float* __restrict__ x,
                                                   const float* __restrict__ Wg,
                                                   float* __restrict__ xw, int n,
                                                   const int* __restrict__ dst,
                                                   int* __restrict__ bh, int E, int gb)
{
    if ((int)blockIdx.x >= gb) {
        // --- bcount part: per-block bucket histogram, LDS atomics only ---
        __shared__ int hist[NBMAX];
        for (int i = threadIdx.x; i < NBMAX; i += 256) hist[i] = 0;
        __syncthreads();
        int g = blockIdx.x - gb;
        int base = g * EPB;
#pragma unroll 4
        for (int j = 0; j < EPB / 256; ++j) {
            int e = base + j * 256 + threadIdx.x;
            if (e < E) atomicAdd(&hist[dst[e] >> BSH], 1);
        }
        __syncthreads();
        int* row = bh + (size_t)g * NBMAX;
        for (int i = threadIdx.x; i < NBMAX; i += 256) row[i] = hist[i];
        return;
    }
    // --- xw part: xw[row] = x[row] @ Wg ---
    int row = blockIdx.x * 256 + threadIdx.x;
    if (row >= n) return;
    float acc[C];
#pragma unroll
    for (int c = 0; c < C; ++c) acc[c] = 0.f;
    const float4* xr = (const float4*)(x + (size_t)row * F);
#pragma unroll 8
    for (int k4 = 0; k4 < F / 4; ++k4) {
        float4 xv = xr[k4];
        const float* w = Wg + k4 * 4 * C;  // uniform -> s_load
#pragma unroll
        for (int j = 0; j < 4; ++j) {
            float xs = (j == 0) ? xv.x : (j == 1) ? xv.y : (j == 2) ? xv.z : xv.w;
#pragma unroll
            for (int c = 0; c < C; ++c)
                acc[c] = fmaf(xs, w[j * C + c], acc[c]);
        }
    }
    float4* o = (float4*)(xw + (size_t)row * C);
#pragma unroll
    for (int q = 0; q < 4; ++q)
        o[q] = make_float4(acc[4 * q + 0], acc[4 * q + 1], acc[4 * q + 2], acc[4 * q + 3]);
}

// Partition + in-block scan. Each block g:
//  1. column pass over bh (thread t owns columns t+256k, k=0..3): accumulates
//     per-bucket totals and records its OWN exclusive prefix (sum over g'<g).
//  2. LDS exclusive scan of the 1024 totals -> bucket starts.
//  3. cur[b] = bucket_start[b] + own_prefix[b]; block 0 publishes bstart[].
//  4. scatter edges into packed[] via LDS cursors.
__global__ __launch_bounds__(256) void k_bscatter(const int* __restrict__ ei,
                                                  const int* __restrict__ bh,
                                                  int* __restrict__ bstart,
                                                  int* __restrict__ packed,
                                                  int E, int geb)
{
    __shared__ int s_excl[NBMAX];
    __shared__ int cur[NBMAX];
    int g = blockIdx.x, t = threadIdx.x;

    int own[4], tot[4];
#pragma unroll
    for (int k = 0; k < 4; ++k) { own[k] = 0; tot[k] = 0; }
    int gg = 0;
    for (; gg + 4 <= geb; gg += 4) {
        int v[4][4];
#pragma unroll
        for (int j = 0; j < 4; ++j)
#pragma unroll
            for (int k = 0; k < 4; ++k)
                v[j][k] = bh[(size_t)(gg + j) * NBMAX + t + 256 * k];
#pragma unroll
        for (int j = 0; j < 4; ++j)
#pragma unroll
            for (int k = 0; k < 4; ++k) {
                if (gg + j == g) own[k] = tot[k];
                tot[k] += v[j][k];
            }
    }
    for (; gg < geb; ++gg) {  // tail (geb=196 is /4, kept for robustness)
#pragma unroll
        for (int k = 0; k < 4; ++k) {
            int v = bh[(size_t)gg * NBMAX + t + 256 * k];
            if (gg == g) own[k] = tot[k];
            tot[k] += v;
        }
    }
#pragma unroll
    for (int k = 0; k < 4; ++k) s_excl[t + 256 * k] = tot[k];
    __syncthreads();

    // exclusive scan of 1024 totals: thread t scans chunk [4t, 4t+4)
    int c0 = s_excl[4 * t], c1 = s_excl[4 * t + 1],
        c2 = s_excl[4 * t + 2], c3 = s_excl[4 * t + 3];
    int csum = c0 + c1 + c2 + c3;
    cur[t] = csum;  // cur reused as chunk-sum scratch
    __syncthreads();
    for (int d = 1; d < 256; d <<= 1) {
        int u = (t >= d) ? cur[t - d] : 0;
        __syncthreads();
        cur[t] += u;
        __syncthreads();
    }
    int chunk_excl = cur[t] - csum;
    __syncthreads();  // all scratch reads of cur[] done before overwrite below

    int e0 = chunk_excl, e1 = e0 + c0, e2 = e1 + c1, e3 = e2 + c2;
    s_excl[4 * t] = e0; s_excl[4 * t + 1] = e1;
    s_excl[4 * t + 2] = e2; s_excl[4 * t + 3] = e3;
    __syncthreads();

#pragma unroll
    for (int k = 0; k < 4; ++k)
        cur[t + 256 * k] = s_excl[t + 256 * k] + own[k];
    if (g == 0) {  // publish bucket starts for k_bcsr (kernel boundary = visible)
#pragma unroll
        for (int k = 0; k < 4; ++k) bstart[t + 256 * k] = s_excl[t + 256 * k];
        if (t == 255) bstart[NBMAX] = e3 + c3;  // total = E
    }
    __syncthreads();

    int base = g * EPB;
#pragma unroll 2
    for (int j = 0; j < EPB / 256; ++j) {
        int e = base + j * 256 + t;
        if (e < E) {
            int d = ei[E + e];
            int s = ei[e];
            int b = d >> BSH;
            int r = atomicAdd(&cur[b], 1);
            packed[r] = s | ((d & (BSZ - 1)) << 17);
        }
    }
}

// Per-bucket CSR build: LDS hist -> local scan -> srcs/starts/cnt/dinv;
// scales this bucket's y rows in place.
__global__ __launch_bounds__(256) void k_bcsr(const int* __restrict__ packed,
                                              const int* __restrict__ bstart,
                                              float* __restrict__ y,
                                              int* __restrict__ srcs,
                                              int* __restrict__ starts,
                                              int* __restrict__ cnt,
                                              float* __restrict__ dinv, int n)
{
    int b = blockIdx.x, t = threadIdx.x;
    __shared__ int hist[BSZ];
    __shared__ int sc[BSZ];
    __shared__ float sdi[BSZ];
    if (t < BSZ) hist[t] = 0;
    __syncthreads();
    int beg = bstart[b], end = bstart[b + 1];
    for (int e = beg + t; e < end; e += 256)
        atomicAdd(&hist[(packed[e] >> 17) & (BSZ - 1)], 1);
    __syncthreads();
    int myc = 0;
    if (t < BSZ) { myc = hist[t]; sc[t] = myc; }
    __syncthreads();
    for (int d = 1; d < BSZ; d <<= 1) {
        int u = 0;
        if (t < BSZ && t >= d) u = sc[t - d];
        __syncthreads();
        if (t < BSZ) sc[t] += u;
        __syncthreads();
    }
    int node0 = b << BSH;
    if (t < BSZ) {
        int lst = sc[t] - myc;   // exclusive local offset
        sc[t] = lst;
        float di = rsqrtf((float)(myc + 1));
        sdi[t] = di;
        int node = node0 + t;
        if (node < n) { starts[node] = beg + lst; cnt[node] = myc; dinv[node] = di; }
        hist[t] = 0;             // reuse as cursor
    }
    __syncthreads();
    for (int e = beg + t; e < end; e += 256) {
        int p = packed[e];
        int dl = (p >> 17) & (BSZ - 1);
        int r = atomicAdd(&hist[dl], 1);
        srcs[beg + sc[dl] + r] = p & 0x1FFFF;
    }
    // scale this bucket's y rows by dinv
    int nn = n - node0; if (nn > BSZ) nn = BSZ;
    if (nn <= 0) return;
    int lim = nn * 4;
    float4* yv = (float4*)(y + (size_t)node0 * C);
    for (int i = t; i < lim; i += 256) {
        float di = sdi[i >> 2];
        float4 v = yv[i];
        v.x *= di; v.y *= di; v.z *= di; v.w *= di;
        yv[i] = v;
    }
}

// Gather (R3 structure) + fused MLP epilogue. 4 threads/node, 64 nodes/block.
// Hidden row staged in LDS; threads 0..63 run the 16->16->32->1 MLP + sigmoid.
__global__ __launch_bounds__(256) void k_gather_mlp(const float* __restrict__ y,
                                                    const int* __restrict__ srcs,
                                                    const int* __restrict__ starts,
                                                    const int* __restrict__ cnt,
                                                    const float* __restrict__ dinv,
                                                    const float* __restrict__ bg,
                                                    const float* __restrict__ W1,
                                                    const float* __restrict__ b1,
                                                    const float* __restrict__ W2,
                                                    const float* __restrict__ b2,
                                                    const float* __restrict__ W3,
                                                    const float* __restrict__ b3,
                                                    float* __restrict__ out, int n)
{
    __shared__ float sh[64][17];  // +1 pad: conflict-free column reads in MLP
    int tid = threadIdx.x;
    int gtid = blockIdx.x * 256 + tid;
    int i = gtid >> 2;
    int q = tid & 3;
    if (i < n) {
        const float4* yv = (const float4*)y;
        float4 acc = yv[(size_t)i * 4 + q];  // self-loop term (y pre-scaled)
        int beg = starts[i];
        int end = beg + cnt[i];
        int e = beg;
        int headEnd = (beg + 3) & ~3;
        if (headEnd > end) headEnd = end;
        for (; e < headEnd; ++e) {
            float4 v = yv[(size_t)srcs[e] * 4 + q];
            acc.x += v.x; acc.y += v.y; acc.z += v.z; acc.w += v.w;
        }
        for (; e + 4 <= end; e += 4) {
            int4 s4 = *(const int4*)(srcs + e);
            float4 v0 = yv[(size_t)s4.x * 4 + q];
            float4 v1 = yv[(size_t)s4.y * 4 + q];
            float4 v2 = yv[(size_t)s4.z * 4 + q];
            float4 v3 = yv[(size_t)s4.w * 4 + q];
            acc.x += v0.x + v1.x + v2.x + v3.x;
            acc.y += v0.y + v1.y + v2.y + v3.y;
            acc.z += v0.z + v1.z + v2.z + v3.z;
            acc.w += v0.w + v1.w + v2.w + v3.w;
        }
        for (; e < end; ++e) {
            float4 v = yv[(size_t)srcs[e] * 4 + q];
            acc.x += v.x; acc.y += v.y; acc.z += v.z; acc.w += v.w;
        }
        float di = dinv[i];
        const float* bq = bg + q * 4;
        int lr = tid >> 2;
        sh[lr][4 * q + 0] = fmaxf(fmaf(acc.x, di, bq[0]), 0.f);
        sh[lr][4 * q + 1] = fmaxf(fmaf(acc.y, di, bq[1]), 0.f);
        sh[lr][4 * q + 2] = fmaxf(fmaf(acc.z, di, bq[2]), 0.f);
        sh[lr][4 * q + 3] = fmaxf(fmaf(acc.w, di, bq[3]), 0.f);
    }
    __syncthreads();
    if (tid < 64) {
        int node = blockIdx.x * 64 + tid;
        if (node < n) {
            float h[16];
#pragma unroll
            for (int k = 0; k < 16; ++k) h[k] = sh[tid][k];
            float h1[16];
#pragma unroll
            for (int c = 0; c < 16; ++c) {
                float s = b1[c];
#pragma unroll
                for (int k = 0; k < 16; ++k) s = fmaf(h[k], W1[k * 16 + c], s);
                h1[c] = fmaxf(s, 0.f);
            }
            float h2[32];
#pragma unroll
            for (int c = 0; c < 32; ++c) {
                float s = b2[c];
#pragma unroll
                for (int k = 0; k < 16; ++k) s = fmaf(h1[k], W2[k * 32 + c], s);
                h2[c] = fmaxf(s, 0.f);
            }
            float s = b3[0];
#pragma unroll
            for (int k = 0; k < 32; ++k) s = fmaf(h2[k], W3[k], s);
            out[node] = 1.f / (1.f + expf(-s));
        }
    }
}

extern "C" void kernel_launch(void* const* d_in, const int* in_sizes, int n_in,
                              void* d_out, int out_size, void* d_ws, size_t ws_size,
                              hipStream_t stream)
{
    const float* x  = (const float*)d_in[0];
    const int*   ei = (const int*)d_in[1];   // [2,E]: src at [e], dst at [E+e]
    const float* Wg = (const float*)d_in[2];
    const float* bg = (const float*)d_in[3];
    const float* W1 = (const float*)d_in[4];
    const float* b1 = (const float*)d_in[5];
    const float* W2 = (const float*)d_in[6];
    const float* b2 = (const float*)d_in[7];
    const float* W3 = (const float*)d_in[8];
    const float* b3 = (const float*)d_in[9];
    float* out = (float*)d_out;

    int n = in_sizes[0] / F;   // 100000
    int E = in_sizes[1] / 2;   // 3200000

    int gb  = (n + 255) / 256;
    int geb = (E + EPB - 1) / EPB;          // 196
    int NB  = (n + BSZ - 1) >> BSH;         // 782

    // ws: y[n*16] | packed[E] | srcs[E] (aliases bh[geb*1024]; disjoint
    //     lifetimes: bh used xw_bcount..bscatter, srcs used bcsr..gather) |
    //     starts[n] | cnt[n] | dinv[n] | bstart[1025]
    char* ws = (char*)d_ws;
    size_t off = 0;
    float* y      = (float*)(ws + off); off += (size_t)n * C * sizeof(float);
    int*   packed = (int*)  (ws + off); off += (size_t)E * sizeof(int);
    int*   srcs   = (int*)  (ws + off);
    int*   bh     = srcs;  // alias, disjoint lifetime
    size_t big = (size_t)E; if ((size_t)geb * NBMAX > big) big = (size_t)geb * NBMAX;
    off += big * sizeof(int);
    int*   starts = (int*)  (ws + off); off += (size_t)((n + 3) & ~3) * sizeof(int);
    int*   cnt    = (int*)  (ws + off); off += (size_t)((n + 3) & ~3) * sizeof(int);
    float* dinv   = (float*)(ws + off); off += (size_t)((n + 3) & ~3) * sizeof(float);
    int*   bstart = (int*)  (ws + off);

    k_xw_bcount<<<gb + geb, 256, 0, stream>>>(x, Wg, y, n, ei + E, bh, E, gb);
    k_bscatter<<<geb, 256, 0, stream>>>(ei, bh, bstart, packed, E, geb);
    k_bcsr<<<NB, 256, 0, stream>>>(packed, bstart, y, srcs, starts, cnt, dinv, n);
    k_gather_mlp<<<(n + 63) / 64, 256, 0, stream>>>(y, srcs, starts, cnt, dinv, bg,
                                                    W1, b1, W2, b2, W3, b3, out, n);
}